// Round 1
// baseline (8825.573 us; speedup 1.0000x reference)
//
#include <hip/hip_runtime.h>

#define TT 1024
#define LOG2E 1.44269504088896340736f

typedef __attribute__((ext_vector_type(8))) short s16x8;
typedef __attribute__((ext_vector_type(4))) float f32x4;
typedef __attribute__((ext_vector_type(4))) unsigned int u32x4;
typedef __attribute__((ext_vector_type(2))) unsigned int u32x2;

__device__ __forceinline__ float ex2(float x){ return __builtin_amdgcn_exp2f(x); }
__device__ __forceinline__ float rcp_(float x){ return __builtin_amdgcn_rcpf(x); }
__device__ __forceinline__ float sigm(float x){ return rcp_(1.f + ex2(-LOG2E*x)); }
__device__ __forceinline__ float tanh_(float x){
  float t = ex2(2.f*LOG2E*x);
  return 1.f - 2.f*rcp_(t + 1.f);
}
__device__ __forceinline__ unsigned short f2bf(float f){
  unsigned int u = __float_as_uint(f);
  u += 0x7fffu + ((u>>16)&1u);
  return (unsigned short)(u>>16);
}
__device__ __forceinline__ float bflo(unsigned int u){ return __uint_as_float(u << 16); }
__device__ __forceinline__ float bfhi(unsigned int u){ return __uint_as_float(u & 0xffff0000u); }

// ---------------------------------------------------------------------------
// Phase 0: pack weights into MFMA B-fragment layout, bf16.
// Wpk layout: [d(2)][tau(66)][s(9)][lane(64)][8 bf16]
//   tau<64 : gate tile, col = 256*(tau&3) + 16*(tau>>2) + (lane&15)
//            k<256 -> Whh[col][k]; 256<=k<275 -> Wih[col][k-256]; else 0
//   tau>=64: y tile (out_W half), col = 16*(tau-64)+(lane&15); k<256 -> out_W[col][d*256+k]
// ---------------------------------------------------------------------------
__global__ __launch_bounds__(256) void pack_weights(
    const float* __restrict__ WhhF, const float* __restrict__ WihF,
    const float* __restrict__ WhhB, const float* __restrict__ WihB,
    const float* __restrict__ outW, unsigned short* __restrict__ Wpk)
{
  int gid = blockIdx.x*256 + threadIdx.x;
  const int TOT = 2*66*9*64;
  if (gid >= TOT) return;
  int l   = gid & 63;
  int s   = (gid>>6) % 9;
  int tau = ((gid>>6)/9) % 66;
  int d   = gid / (66*9*64);
  const float* Whh = d ? WhhB : WhhF;
  const float* Wih = d ? WihB : WihF;
  int kb = s*32 + (l>>4)*8;
  int cr = l & 15;
  unsigned short v[8];
  #pragma unroll
  for (int j=0;j<8;j++){
    int k = kb + j;
    float val = 0.f;
    if (tau < 64){
      int col = 256*(tau&3) + 16*(tau>>2) + cr;
      if (k < 256)      val = Whh[col*256 + k];
      else if (k < 275) val = Wih[col*19 + (k-256)];
    } else {
      int col = 16*(tau-64) + cr;
      if (k < 256)      val = outW[col*512 + d*256 + k];
    }
    v[j] = f2bf(val);
  }
  u32x4 pk;
  pk[0] = (unsigned)v[0] | ((unsigned)v[1]<<16);
  pk[1] = (unsigned)v[2] | ((unsigned)v[3]<<16);
  pk[2] = (unsigned)v[4] | ((unsigned)v[5]<<16);
  pk[3] = (unsigned)v[6] | ((unsigned)v[7]<<16);
  *(u32x4*)&Wpk[(size_t)gid*8] = pk;
}

// ---------------------------------------------------------------------------
// Phase 1: persistent per-(dir, batch-group) LSTM.
// 16 blocks x 512 threads (8 waves). Wave w owns gate tiles tau=8w..8w+7:
//   tile m: gate type g=m&3, unit block u=2w+(m>>2), cols 256*g+16*u..+15.
// MFMA C layout (col=lane&15,row=quad*4+reg) => each lane's accs hold
// i/f/g/o for unit kh=16u+(lane&15), batches quad*4+0..3 -> in-register LSTM cell.
// A (h|x) lives in LDS in A-fragment order [s(9)][lane(64)][8 bf16], double buffered.
// Waves 0/1 additionally compute y = out_W_half @ h (2 tiles) -> y_ws bf16.
// ---------------------------------------------------------------------------
__global__ __launch_bounds__(512, 2) void lstm_kernel(
    const float* __restrict__ loc, const float* __restrict__ tds,
    const int* __restrict__ dlen,
    const float* __restrict__ timeW, const float* __restrict__ timeB,
    const float* __restrict__ bF, const float* __restrict__ bB,
    const unsigned short* __restrict__ Wpk, unsigned short* __restrict__ y_ws)
{
  __shared__ alignas(16) unsigned short Albuf[2][4608];   // 2 x 9*64*8 bf16
  int tid = threadIdx.x;
  int w = tid >> 6, l = tid & 63;
  int bid = blockIdx.x;
  int d = bid >> 3, grp = bid & 7;
  int quad = l >> 4, cr = l & 15;

  { // zero both A buffers (h part + x pad)
    unsigned int* az = (unsigned int*)&Albuf[0][0];
    for (int i = tid; i < 4608; i += 512) az[i] = 0u;
  }

  int lens[4];
  #pragma unroll
  for (int i=0;i<4;i++) lens[i] = dlen[grp*16 + quad*4 + i];
  int maxlen = dlen[grp*16];               // lengths sorted descending

  const float* bias = d ? bB : bF;
  float biasr[8];
  #pragma unroll
  for (int m=0;m<8;m++){
    int col = 256*(m&3) + 16*(2*w + (m>>2)) + cr;
    biasr[m] = bias[col];
  }

  const s16x8* BP = (const s16x8*)Wpk;
  int btile  = (d*66 + 8*w)*9*64;          // + (m*9+s)*64 + l
  int bytile = (d*66 + 64 + w)*9*64;       // + s*64 + l
  bool has_y = (w < 2);

  // wave-3 time-embedding weights
  int jj = (quad < 3) ? quad : 2;
  bool act3 = (w==3) && (quad < 3);
  float tw[8]; float tb0 = 0.f;
  if (w == 3){
    #pragma unroll
    for (int dd=0; dd<8; dd++) tw[dd] = timeW[jj*8+dd];
    tb0 = timeB[jj];
  }

  float c[8], h[8];
  #pragma unroll
  for (int i=0;i<8;i++){ c[i]=0.f; h[i]=0.f; }

  __syncthreads();   // zero done

  int t0 = d ? (maxlen-1) : 0;
  { // prologue: x(t0) into buf 0
    int tn = t0;
    f32x4 xa = {0.f,0.f,0.f,0.f}, ta0 = {0.f,0.f,0.f,0.f}, ta1 = {0.f,0.f,0.f,0.f};
    if (w==2){
      const float* px = &loc[(((size_t)(grp*16 + (l>>2)))*TT + tn)*16 + (l&3)*4];
      xa = *(const f32x4*)px;
    }
    if (act3){
      const float* pt = &tds[(((size_t)(grp*16 + cr))*TT + tn)*8];
      ta0 = *(const f32x4*)pt;
      ta1 = *(const f32x4*)(pt+4);
    }
    if (w==2){
      int q = l&3, b16 = l>>2;
      unsigned int u0 = (unsigned)f2bf(xa[0]) | ((unsigned)f2bf(xa[1])<<16);
      unsigned int u1 = (unsigned)f2bf(xa[2]) | ((unsigned)f2bf(xa[3])<<16);
      int idx = 4096 + (q>>1)*128 + b16*8 + (q&1)*4;
      u32x2 uu = {u0, u1};
      *(u32x2*)&Albuf[0][idx] = uu;
    }
    if (act3){
      float td = tb0;
      #pragma unroll
      for (int dd=0; dd<4; dd++) td += ta0[dd]*tw[dd] + ta1[dd]*tw[4+dd];
      Albuf[0][4096 + 256 + cr*8 + jj] = f2bf(td);
    }
  }
  __syncthreads();

  int p = 0;
  for (int vs = 0; vs <= maxlen; vs++){
    int tg = d ? (maxlen-1-vs) : vs;       // gates time (valid when vs<maxlen)
    int ty = d ? (maxlen-vs)   : (vs-1);   // y time (valid when vs>0)
    bool do_g = (vs < maxlen);

    const s16x8* ap = (const s16x8*)&Albuf[p][0];
    s16x8 a[9];
    #pragma unroll
    for (int s=0;s<9;s++) a[s] = ap[s*64 + l];

    // prefetch x for next step (HBM latency hidden behind mfma phase)
    int tn = d ? (tg-1) : (tg+1);
    bool xval = do_g && (tn >= 0) && (tn < TT);
    f32x4 xa = {0.f,0.f,0.f,0.f}, ta0 = {0.f,0.f,0.f,0.f}, ta1 = {0.f,0.f,0.f,0.f};
    if (w==2 && xval){
      const float* px = &loc[(((size_t)(grp*16 + (l>>2)))*TT + tn)*16 + (l&3)*4];
      xa = *(const f32x4*)px;
    }
    if (act3 && xval){
      const float* pt = &tds[(((size_t)(grp*16 + cr))*TT + tn)*8];
      ta0 = *(const f32x4*)pt;
      ta1 = *(const f32x4*)(pt+4);
    }

    // ---- y projection of h-state (state after step ty) ----
    if (has_y && vs > 0){
      f32x4 yacc;
      s16x8 yb0 = BP[bytile + 0*64 + l];
      #pragma unroll
      for (int s=0;s<9;s++){
        s16x8 ybn;
        if (s < 8) ybn = BP[bytile + (s+1)*64 + l];
        if (s == 0){
          f32x4 zz = {0.f,0.f,0.f,0.f};
          yacc = __builtin_amdgcn_mfma_f32_16x16x32_bf16(a[0], yb0, zz, 0,0,0);
        } else {
          yacc = __builtin_amdgcn_mfma_f32_16x16x32_bf16(a[s], yb0, yacc, 0,0,0);
        }
        yb0 = ybn;
      }
      size_t ybase = ((((size_t)d*8 + grp)*TT + (size_t)ty)*16)*32;
      #pragma unroll
      for (int i=0;i<4;i++)
        y_ws[ybase + (size_t)(quad*4+i)*32 + 16*w + cr] = f2bf(yacc[i]);
    }

    // ---- gates + cell update ----
    if (do_g){
      f32x4 acc[8];
      s16x8 bb[2][8];
      #pragma unroll
      for (int m=0;m<8;m++) bb[0][m] = BP[btile + (m*9+0)*64 + l];
      #pragma unroll
      for (int s=0;s<9;s++){
        const int cu = s & 1, nx = cu ^ 1;
        if (s < 8){
          #pragma unroll
          for (int m=0;m<8;m++) bb[nx][m] = BP[btile + (m*9+s+1)*64 + l];
        }
        #pragma unroll
        for (int m=0;m<8;m++){
          if (s == 0){
            f32x4 zz = {0.f,0.f,0.f,0.f};
            acc[m] = __builtin_amdgcn_mfma_f32_16x16x32_bf16(a[0], bb[cu][m], zz, 0,0,0);
          } else {
            acc[m] = __builtin_amdgcn_mfma_f32_16x16x32_bf16(a[s], bb[cu][m], acc[m], 0,0,0);
          }
        }
      }

      int wb = p ^ 1;
      #pragma unroll
      for (int u2=0; u2<2; u2++){
        int kh = 16*(2*w + u2) + cr;
        int s_ = kh >> 5, q_ = (kh>>3)&3, ko = kh & 7;
        #pragma unroll
        for (int i=0;i<4;i++){
          float ig = acc[u2*4+0][i] + biasr[u2*4+0];
          float fg = acc[u2*4+1][i] + biasr[u2*4+1];
          float gg = acc[u2*4+2][i] + biasr[u2*4+2];
          float og = acc[u2*4+3][i] + biasr[u2*4+3];
          float cn = sigm(fg)*c[u2*4+i] + sigm(ig)*tanh_(gg);
          float hn = sigm(og)*tanh_(cn);
          bool mk = (tg < lens[i]);
          c[u2*4+i] = mk ? cn : c[u2*4+i];
          h[u2*4+i] = mk ? hn : h[u2*4+i];
          Albuf[wb][s_*512 + q_*128 + (quad*4+i)*8 + ko] = f2bf(h[u2*4+i]);
        }
      }
      // x(t_next) into the buffer about to be consumed
      if (w==2){
        int q = l&3, b16 = l>>2;
        unsigned int u0 = (unsigned)f2bf(xa[0]) | ((unsigned)f2bf(xa[1])<<16);
        unsigned int u1 = (unsigned)f2bf(xa[2]) | ((unsigned)f2bf(xa[3])<<16);
        int idx = 4096 + (q>>1)*128 + b16*8 + (q&1)*4;
        u32x2 uu = {u0, u1};
        *(u32x2*)&Albuf[wb][idx] = uu;
      }
      if (act3){
        float td = tb0;
        #pragma unroll
        for (int dd=0; dd<4; dd++) td += ta0[dd]*tw[dd] + ta1[dd]*tw[4+dd];
        Albuf[wb][4096 + 256 + cr*8 + jj] = f2bf(td);
      }
    }
    __syncthreads();
    p ^= 1;
  }
}

// ---------------------------------------------------------------------------
// Phase 2: per-batch head: tanh(y_f+y_b+addr_feat) . comb_W, masked log_softmax.
// ---------------------------------------------------------------------------
__global__ __launch_bounds__(256) void combine_kernel(
    const unsigned short* __restrict__ y_ws,
    const float* __restrict__ addr, const int* __restrict__ addr_type,
    const float* __restrict__ poi, const float* __restrict__ addrW,
    const float* __restrict__ addrB, const float* __restrict__ combW,
    const int* __restrict__ dlen, float* __restrict__ out)
{
  int b = blockIdx.x, tid = threadIdx.x;
  int grp = b >> 4, row = b & 15;
  __shared__ float af[32], cw[32], red[256];
  if (tid < 32){
    float s = addrB[tid] + addrW[tid*4]*addr[b];
    int at = addr_type[b];
    #pragma unroll
    for (int e=0;e<3;e++) s += addrW[tid*4+1+e]*poi[at*3+e];
    af[tid] = s;
    cw[tid] = combW[tid];
  }
  __syncthreads();
  int len = dlen[b];
  float sv[4];
  float lmax = -3.0e38f;
  #pragma unroll
  for (int kk=0;kk<4;kk++){
    int t = tid + kk*256;
    const u32x4* pf = (const u32x4*)(y_ws + ((((size_t)grp)*TT + t)*16 + row)*32);
    const u32x4* pb = (const u32x4*)(y_ws + ((((size_t)(8+grp))*TT + t)*16 + row)*32);
    float s = 0.f;
    #pragma unroll
    for (int ck=0; ck<4; ck++){
      u32x4 uf = pf[ck], ub = pb[ck];
      #pragma unroll
      for (int e=0;e<4;e++){
        int j = ck*8 + e*2;
        float v0 = bflo(uf[e]) + bflo(ub[e]) + af[j];
        float v1 = bfhi(uf[e]) + bfhi(ub[e]) + af[j+1];
        s += cw[j]*tanh_(v0) + cw[j+1]*tanh_(v1);
      }
    }
    sv[kk] = s;
    if (t < len) lmax = fmaxf(lmax, s);
  }
  red[tid] = lmax; __syncthreads();
  for (int off=128; off>0; off>>=1){
    if (tid < off) red[tid] = fmaxf(red[tid], red[tid+off]);
    __syncthreads();
  }
  float gmax = red[0];
  __syncthreads();
  float ls = 0.f;
  #pragma unroll
  for (int kk=0;kk<4;kk++){
    int t = tid + kk*256;
    if (t < len) ls += ex2(LOG2E*(sv[kk]-gmax));
  }
  red[tid] = ls; __syncthreads();
  for (int off=128; off>0; off>>=1){
    if (tid < off) red[tid] += red[tid+off];
    __syncthreads();
  }
  float lnz = __builtin_amdgcn_logf(red[0]) * (1.f/LOG2E);
  #pragma unroll
  for (int kk=0;kk<4;kk++){
    int t = tid + kk*256;
    out[(size_t)b*TT + t] = (t < len) ? (sv[kk]-gmax-lnz) : 0.f;
  }
}

// ---------------------------------------------------------------------------
extern "C" void kernel_launch(void* const* d_in, const int* in_sizes, int n_in,
                              void* d_out, int out_size, void* d_ws, size_t ws_size,
                              hipStream_t stream)
{
  const float* addr  = (const float*)d_in[0];
  const int*   atyp  = (const int*)d_in[1];
  const float* loc   = (const float*)d_in[2];
  const float* tdsq  = (const float*)d_in[3];
  const int*   dlen  = (const int*)d_in[4];
  const float* poi   = (const float*)d_in[5];
  const float* timeW = (const float*)d_in[6];
  const float* timeB = (const float*)d_in[7];
  const float* addrW = (const float*)d_in[8];
  const float* addrB = (const float*)d_in[9];
  const float* WihF  = (const float*)d_in[10];
  const float* WhhF  = (const float*)d_in[11];
  const float* bF    = (const float*)d_in[12];
  const float* WihB  = (const float*)d_in[13];
  const float* WhhB  = (const float*)d_in[14];
  const float* bB    = (const float*)d_in[15];
  const float* outW  = (const float*)d_in[16];
  const float* combW = (const float*)d_in[17];

  unsigned short* Wpk  = (unsigned short*)d_ws;                       // 1,216,512 B
  unsigned short* y_ws = (unsigned short*)((char*)d_ws + 1216512);    // 16,777,216 B
  float* outp = (float*)d_out;

  pack_weights<<<297, 256, 0, stream>>>(WhhF, WihF, WhhB, WihB, outW, Wpk);
  lstm_kernel<<<16, 512, 0, stream>>>(loc, tdsq, dlen, timeW, timeB, bF, bB, Wpk, y_ws);
  combine_kernel<<<128, 256, 0, stream>>>(y_ws, addr, atyp, poi, addrW, addrB, combW, dlen, outp);
}

// Round 2
// 6722.174 us; speedup vs baseline: 1.3129x; 1.3129x over previous
//
#include <hip/hip_runtime.h>

#define TT 1024
#define LOG2E 1.44269504088896340736f

typedef __attribute__((ext_vector_type(8))) short s16x8;
typedef __attribute__((ext_vector_type(4))) float f32x4;
typedef __attribute__((ext_vector_type(4))) unsigned int u32x4;
typedef __attribute__((ext_vector_type(2))) unsigned int u32x2;

__device__ __forceinline__ float ex2(float x){ return __builtin_amdgcn_exp2f(x); }
__device__ __forceinline__ float rcp_(float x){ return __builtin_amdgcn_rcpf(x); }
__device__ __forceinline__ float sigm(float x){ return rcp_(1.f + ex2(-LOG2E*x)); }
__device__ __forceinline__ float tanh_(float x){
  float t = ex2(2.f*LOG2E*x);
  return 1.f - 2.f*rcp_(t + 1.f);
}
__device__ __forceinline__ unsigned short f2bf(float f){
  unsigned int u = __float_as_uint(f);
  u += 0x7fffu + ((u>>16)&1u);
  return (unsigned short)(u>>16);
}
__device__ __forceinline__ float bflo(unsigned int u){ return __uint_as_float(u << 16); }
__device__ __forceinline__ float bfhi(unsigned int u){ return __uint_as_float(u & 0xffff0000u); }

// ---------------------------------------------------------------------------
// Phase 0: pack weights into MFMA B-fragment layout, bf16. (unchanged)
// Wpk layout: [d(2)][tau(66)][s(9)][lane(64)][8 bf16]
//   tau<64 : gate tile, col = 256*(tau&3) + 16*(tau>>2) + (lane&15)
//            k<256 -> Whh[col][k]; 256<=k<275 -> Wih[col][k-256]; else 0
//   tau>=64: y tile (out_W half), col = 16*(tau-64)+(lane&15); k<256 -> out_W[col][d*256+k]
// ---------------------------------------------------------------------------
__global__ __launch_bounds__(256) void pack_weights(
    const float* __restrict__ WhhF, const float* __restrict__ WihF,
    const float* __restrict__ WhhB, const float* __restrict__ WihB,
    const float* __restrict__ outW, unsigned short* __restrict__ Wpk)
{
  int gid = blockIdx.x*256 + threadIdx.x;
  const int TOT = 2*66*9*64;
  if (gid >= TOT) return;
  int l   = gid & 63;
  int s   = (gid>>6) % 9;
  int tau = ((gid>>6)/9) % 66;
  int d   = gid / (66*9*64);
  const float* Whh = d ? WhhB : WhhF;
  const float* Wih = d ? WihB : WihF;
  int kb = s*32 + (l>>4)*8;
  int cr = l & 15;
  unsigned short v[8];
  #pragma unroll
  for (int j=0;j<8;j++){
    int k = kb + j;
    float val = 0.f;
    if (tau < 64){
      int col = 256*(tau&3) + 16*(tau>>2) + cr;
      if (k < 256)      val = Whh[col*256 + k];
      else if (k < 275) val = Wih[col*19 + (k-256)];
    } else {
      int col = 16*(tau-64) + cr;
      if (k < 256)      val = outW[col*512 + d*256 + k];
    }
    v[j] = f2bf(val);
  }
  u32x4 pk;
  pk[0] = (unsigned)v[0] | ((unsigned)v[1]<<16);
  pk[1] = (unsigned)v[2] | ((unsigned)v[3]<<16);
  pk[2] = (unsigned)v[4] | ((unsigned)v[5]<<16);
  pk[3] = (unsigned)v[6] | ((unsigned)v[7]<<16);
  *(u32x4*)&Wpk[(size_t)gid*8] = pk;
}

// ---------------------------------------------------------------------------
// Phase 1: persistent per-(dir, batch-group) LSTM.
// 16 blocks x 1024 threads (16 waves = 4 waves/SIMD for latency hiding).
// Wave w owns unit block u=w (16 hidden units), all 4 gates: tiles tau=4w+g,
//   gate g cols = 256*g + 16*w .. +15.
// MFMA C layout (col=lane&15,row=quad*4+reg) => each lane's 4 accs hold
// i/f/g/o for unit kh=16w+(lane&15), batches quad*4+0..3 -> in-register cell.
// A (h|x) in LDS in A-fragment order [s(9)][lane(64)][8 bf16], double buffered;
// A fragments are rolled through 2 registers (LDS prefetch) to stay <=128 VGPR.
// Waves 0/1 additionally compute y = out_W_half @ h -> y_ws bf16.
// Waves 2/3 stage next step's x (loc / time-embed) into the next A buffer.
// ---------------------------------------------------------------------------
__global__ __launch_bounds__(1024) void lstm_kernel(
    const float* __restrict__ loc, const float* __restrict__ tds,
    const int* __restrict__ dlen,
    const float* __restrict__ timeW, const float* __restrict__ timeB,
    const float* __restrict__ bF, const float* __restrict__ bB,
    const unsigned short* __restrict__ Wpk, unsigned short* __restrict__ y_ws)
{
  __shared__ alignas(16) unsigned short Albuf[2][4608];   // 2 x 9*64*8 bf16
  int tid = threadIdx.x;
  int w = tid >> 6, l = tid & 63;
  int bid = blockIdx.x;
  int d = bid >> 3, grp = bid & 7;
  int quad = l >> 4, cr = l & 15;

  { // zero both A buffers (h part + x pad)
    unsigned int* az = (unsigned int*)&Albuf[0][0];
    for (int i = tid; i < 4608; i += 1024) az[i] = 0u;
  }

  int lens[4];
  #pragma unroll
  for (int i=0;i<4;i++) lens[i] = dlen[grp*16 + quad*4 + i];
  int maxlen = dlen[grp*16];               // lengths sorted descending

  const float* bias = d ? bB : bF;
  float biasr[4];
  #pragma unroll
  for (int g=0;g<4;g++) biasr[g] = bias[256*g + 16*w + cr];

  const s16x8* BP = (const s16x8*)Wpk;
  int btile  = (d*66 + 4*w)*9*64;          // + (g*9+s)*64 + l
  int bytile = (d*66 + 64 + w)*9*64;       // + s*64 + l   (waves 0/1)
  bool has_y = (w < 2);

  // wave-3 time-embedding weights
  int jj = (quad < 3) ? quad : 2;
  bool act3 = (w==3) && (quad < 3);
  float tw[8]; float tb0 = 0.f;
  if (w == 3){
    #pragma unroll
    for (int dd=0; dd<8; dd++) tw[dd] = timeW[jj*8+dd];
    tb0 = timeB[jj];
  }

  float c[4], h[4];
  #pragma unroll
  for (int i=0;i<4;i++){ c[i]=0.f; h[i]=0.f; }

  __syncthreads();   // zero done

  int t0 = d ? (maxlen-1) : 0;
  { // prologue: x(t0) into buf 0
    int tn = t0;
    f32x4 xa = {0.f,0.f,0.f,0.f}, ta0 = {0.f,0.f,0.f,0.f}, ta1 = {0.f,0.f,0.f,0.f};
    if (w==2){
      const float* px = &loc[(((size_t)(grp*16 + (l>>2)))*TT + tn)*16 + (l&3)*4];
      xa = *(const f32x4*)px;
    }
    if (act3){
      const float* pt = &tds[(((size_t)(grp*16 + cr))*TT + tn)*8];
      ta0 = *(const f32x4*)pt;
      ta1 = *(const f32x4*)(pt+4);
    }
    if (w==2){
      int q = l&3, b16 = l>>2;
      unsigned int u0 = (unsigned)f2bf(xa[0]) | ((unsigned)f2bf(xa[1])<<16);
      unsigned int u1 = (unsigned)f2bf(xa[2]) | ((unsigned)f2bf(xa[3])<<16);
      int idx = 4096 + (q>>1)*128 + b16*8 + (q&1)*4;
      u32x2 uu = {u0, u1};
      *(u32x2*)&Albuf[0][idx] = uu;
    }
    if (act3){
      float td = tb0;
      #pragma unroll
      for (int dd=0; dd<4; dd++) td += ta0[dd]*tw[dd] + ta1[dd]*tw[4+dd];
      Albuf[0][4096 + 256 + cr*8 + jj] = f2bf(td);
    }
  }
  __syncthreads();

  int p = 0;
  for (int vs = 0; vs <= maxlen; vs++){
    int tg = d ? (maxlen-1-vs) : vs;       // gates time (valid when vs<maxlen)
    int ty = d ? (maxlen-vs)   : (vs-1);   // y time (valid when vs>0)
    bool do_g = (vs < maxlen);

    const s16x8* ap = (const s16x8*)&Albuf[p][0];

    // prefetch x for next step (HBM latency hidden behind mfma phase)
    int tn = d ? (tg-1) : (tg+1);
    bool xval = do_g && (tn >= 0) && (tn < TT);
    f32x4 xa = {0.f,0.f,0.f,0.f}, ta0 = {0.f,0.f,0.f,0.f}, ta1 = {0.f,0.f,0.f,0.f};
    if (w==2 && xval){
      const float* px = &loc[(((size_t)(grp*16 + (l>>2)))*TT + tn)*16 + (l&3)*4];
      xa = *(const f32x4*)px;
    }
    if (act3 && xval){
      const float* pt = &tds[(((size_t)(grp*16 + cr))*TT + tn)*8];
      ta0 = *(const f32x4*)pt;
      ta1 = *(const f32x4*)(pt+4);
    }

    // ---- y projection of h-state (state after step ty), waves 0/1 ----
    if (has_y && vs > 0){
      f32x4 yacc;
      s16x8 ya  = ap[l], yan;
      s16x8 yb0 = BP[bytile + l], ybn;
      #pragma unroll
      for (int s=0;s<9;s++){
        if (s < 8){
          yan = ap[(s+1)*64 + l];
          ybn = BP[bytile + (s+1)*64 + l];
        }
        if (s == 0){
          f32x4 zz = {0.f,0.f,0.f,0.f};
          yacc = __builtin_amdgcn_mfma_f32_16x16x32_bf16(ya, yb0, zz, 0,0,0);
        } else {
          yacc = __builtin_amdgcn_mfma_f32_16x16x32_bf16(ya, yb0, yacc, 0,0,0);
        }
        ya = yan; yb0 = ybn;
      }
      size_t ybase = ((((size_t)d*8 + grp)*TT + (size_t)ty)*16)*32;
      #pragma unroll
      for (int i=0;i<4;i++)
        y_ws[ybase + (size_t)(quad*4+i)*32 + 16*w + cr] = f2bf(yacc[i]);
    }

    // ---- gates + cell update ----
    if (do_g){
      f32x4 acc[4];
      s16x8 bb[2][4];
      s16x8 a_c = ap[l], a_n;
      #pragma unroll
      for (int g=0;g<4;g++) bb[0][g] = BP[btile + (g*9)*64 + l];
      #pragma unroll
      for (int s=0;s<9;s++){
        const int cu = s & 1, nx = cu ^ 1;
        if (s < 8){
          a_n = ap[(s+1)*64 + l];
          #pragma unroll
          for (int g=0;g<4;g++) bb[nx][g] = BP[btile + (g*9+s+1)*64 + l];
        }
        #pragma unroll
        for (int g=0;g<4;g++){
          if (s == 0){
            f32x4 zz = {0.f,0.f,0.f,0.f};
            acc[g] = __builtin_amdgcn_mfma_f32_16x16x32_bf16(a_c, bb[cu][g], zz, 0,0,0);
          } else {
            acc[g] = __builtin_amdgcn_mfma_f32_16x16x32_bf16(a_c, bb[cu][g], acc[g], 0,0,0);
          }
        }
        a_c = a_n;
      }

      int wb = p ^ 1;
      int kh = 16*w + cr;
      int s_ = kh >> 5, q_ = (kh>>3)&3, ko = kh & 7;
      #pragma unroll
      for (int i=0;i<4;i++){
        float ig = acc[0][i] + biasr[0];
        float fg = acc[1][i] + biasr[1];
        float gg = acc[2][i] + biasr[2];
        float og = acc[3][i] + biasr[3];
        float cn = sigm(fg)*c[i] + sigm(ig)*tanh_(gg);
        float hn = sigm(og)*tanh_(cn);
        bool mk = (tg < lens[i]);
        c[i] = mk ? cn : c[i];
        h[i] = mk ? hn : h[i];
        Albuf[wb][s_*512 + q_*128 + (quad*4+i)*8 + ko] = f2bf(h[i]);
      }
      // x(t_next) into the buffer about to be consumed
      if (w==2){
        int q = l&3, b16 = l>>2;
        unsigned int u0 = (unsigned)f2bf(xa[0]) | ((unsigned)f2bf(xa[1])<<16);
        unsigned int u1 = (unsigned)f2bf(xa[2]) | ((unsigned)f2bf(xa[3])<<16);
        int idx = 4096 + (q>>1)*128 + b16*8 + (q&1)*4;
        u32x2 uu = {u0, u1};
        *(u32x2*)&Albuf[wb][idx] = uu;
      }
      if (act3){
        float td = tb0;
        #pragma unroll
        for (int dd=0; dd<4; dd++) td += ta0[dd]*tw[dd] + ta1[dd]*tw[4+dd];
        Albuf[wb][4096 + 256 + cr*8 + jj] = f2bf(td);
      }
    }
    __syncthreads();
    p ^= 1;
  }
}

// ---------------------------------------------------------------------------
// Phase 2: per-batch head: tanh(y_f+y_b+addr_feat) . comb_W, masked log_softmax.
// ---------------------------------------------------------------------------
__global__ __launch_bounds__(256) void combine_kernel(
    const unsigned short* __restrict__ y_ws,
    const float* __restrict__ addr, const int* __restrict__ addr_type,
    const float* __restrict__ poi, const float* __restrict__ addrW,
    const float* __restrict__ addrB, const float* __restrict__ combW,
    const int* __restrict__ dlen, float* __restrict__ out)
{
  int b = blockIdx.x, tid = threadIdx.x;
  int grp = b >> 4, row = b & 15;
  __shared__ float af[32], cw[32], red[256];
  if (tid < 32){
    float s = addrB[tid] + addrW[tid*4]*addr[b];
    int at = addr_type[b];
    #pragma unroll
    for (int e=0;e<3;e++) s += addrW[tid*4+1+e]*poi[at*3+e];
    af[tid] = s;
    cw[tid] = combW[tid];
  }
  __syncthreads();
  int len = dlen[b];
  float sv[4];
  float lmax = -3.0e38f;
  #pragma unroll
  for (int kk=0;kk<4;kk++){
    int t = tid + kk*256;
    const u32x4* pf = (const u32x4*)(y_ws + ((((size_t)grp)*TT + t)*16 + row)*32);
    const u32x4* pb = (const u32x4*)(y_ws + ((((size_t)(8+grp))*TT + t)*16 + row)*32);
    float s = 0.f;
    #pragma unroll
    for (int ck=0; ck<4; ck++){
      u32x4 uf = pf[ck], ub = pb[ck];
      #pragma unroll
      for (int e=0;e<4;e++){
        int j = ck*8 + e*2;
        float v0 = bflo(uf[e]) + bflo(ub[e]) + af[j];
        float v1 = bfhi(uf[e]) + bfhi(ub[e]) + af[j+1];
        s += cw[j]*tanh_(v0) + cw[j+1]*tanh_(v1);
      }
    }
    sv[kk] = s;
    if (t < len) lmax = fmaxf(lmax, s);
  }
  red[tid] = lmax; __syncthreads();
  for (int off=128; off>0; off>>=1){
    if (tid < off) red[tid] = fmaxf(red[tid], red[tid+off]);
    __syncthreads();
  }
  float gmax = red[0];
  __syncthreads();
  float ls = 0.f;
  #pragma unroll
  for (int kk=0;kk<4;kk++){
    int t = tid + kk*256;
    if (t < len) ls += ex2(LOG2E*(sv[kk]-gmax));
  }
  red[tid] = ls; __syncthreads();
  for (int off=128; off>0; off>>=1){
    if (tid < off) red[tid] += red[tid+off];
    __syncthreads();
  }
  float lnz = __builtin_amdgcn_logf(red[0]) * (1.f/LOG2E);
  #pragma unroll
  for (int kk=0;kk<4;kk++){
    int t = tid + kk*256;
    out[(size_t)b*TT + t] = (t < len) ? (sv[kk]-gmax-lnz) : 0.f;
  }
}

// ---------------------------------------------------------------------------
extern "C" void kernel_launch(void* const* d_in, const int* in_sizes, int n_in,
                              void* d_out, int out_size, void* d_ws, size_t ws_size,
                              hipStream_t stream)
{
  const float* addr  = (const float*)d_in[0];
  const int*   atyp  = (const int*)d_in[1];
  const float* loc   = (const float*)d_in[2];
  const float* tdsq  = (const float*)d_in[3];
  const int*   dlen  = (const int*)d_in[4];
  const float* poi   = (const float*)d_in[5];
  const float* timeW = (const float*)d_in[6];
  const float* timeB = (const float*)d_in[7];
  const float* addrW = (const float*)d_in[8];
  const float* addrB = (const float*)d_in[9];
  const float* WihF  = (const float*)d_in[10];
  const float* WhhF  = (const float*)d_in[11];
  const float* bF    = (const float*)d_in[12];
  const float* WihB  = (const float*)d_in[13];
  const float* WhhB  = (const float*)d_in[14];
  const float* bB    = (const float*)d_in[15];
  const float* outW  = (const float*)d_in[16];
  const float* combW = (const float*)d_in[17];

  unsigned short* Wpk  = (unsigned short*)d_ws;                       // 1,216,512 B
  unsigned short* y_ws = (unsigned short*)((char*)d_ws + 1216512);    // 16,777,216 B
  float* outp = (float*)d_out;

  pack_weights<<<297, 256, 0, stream>>>(WhhF, WihF, WhhB, WihB, outW, Wpk);
  lstm_kernel<<<16, 1024, 0, stream>>>(loc, tdsq, dlen, timeW, timeB, bF, bB, Wpk, y_ws);
  combine_kernel<<<128, 256, 0, stream>>>(y_ws, addr, atyp, poi, addrW, addrB, combW, dlen, outp);
}